// Round 8
// baseline (191.436 us; speedup 1.0000x reference)
//
#include <hip/hip_runtime.h>
#include <math.h>

#define HD 128
#define WD 128
#define WP 130              // padded width/height (1-halo)
#define CIN 64
#define COUT 64
#define NB 4
#define K2 9
#define HW (HD*WD)          // 16384
#define CK 576              // CIN*K2, K of the main GEMM (k-major permuted: r' = k*64+c)
#define TP 32               // pixels per block (fused kernel)
#define TPF 16              // pixels per block (fallback kernel)
#define NKK 18              // K-steps of 32

#define WAM   (4 * NKK * 64 * 8)             // 36864 shorts main A-frag buffer (fp16 bits)
#define XTP   ((size_t)NB * WP * WP * CIN)   // 4326400 shorts (padded NHWC fp16 x)
#define OFFSZ ((size_t)NB * K2 * HW)         // 589824 elements per param plane / fallback
#define WTSZ  ((size_t)CK * COUT)            // fallback

// pre_kernel block partition: transpose | halo | waM prep | conv+params
#define PRE_T 1024
#define PRE_H 65
#define PRE_W 144                             // WAM/256
#define PRE_C 256                             // 65536 pixels / 256
#define HALO_PER_N 33024                      // halo shorts per image
#define HALO_W8 16512                         // total 8-short zero units

typedef __attribute__((ext_vector_type(8))) short short8;
typedef __attribute__((ext_vector_type(4))) float f32x4;
typedef _Float16 half8 __attribute__((ext_vector_type(8)));
typedef _Float16 half2v __attribute__((ext_vector_type(2)));

// fp32 -> fp16 bits (scalar, RTN)
__device__ inline short f2h(float v) {
    _Float16 h = (_Float16)v;
    short s; __builtin_memcpy(&s, &h, 2); return s;
}
// pack two fp32 -> dword of two fp16 (v_cvt_pkrtz_f16_f32, 1 instr)
__device__ inline unsigned int pack_f16(float a, float b) {
    auto h = __builtin_amdgcn_cvt_pkrtz(a, b);
    unsigned int u; __builtin_memcpy(&u, &h, 4); return u;
}
// duplicate one fp32 into both halves of a packed fp16 pair
__device__ inline half2v dup_h2(float a) {
    auto h = __builtin_amdgcn_cvt_pkrtz(a, a);
    half2v r; __builtin_memcpy(&r, &h, 4); return r;
}

// ---------------- merged pre-kernel: transpose | halo | waM prep | conv+params ----------------
// LDS: union region, max 32256 B (conv weight cache) -> 5 blocks/CU
__global__ __launch_bounds__(256) void pre_kernel(
    const float* __restrict__ x,
    const float* __restrict__ weight,
    const float* __restrict__ w_off, const float* __restrict__ b_off,
    const float* __restrict__ w_mask, const float* __restrict__ b_mask,
    unsigned short* __restrict__ xp,
    short* __restrict__ mhi,
    float* __restrict__ wyP, float* __restrict__ wxP,
    unsigned int* __restrict__ metaP)
{
    __shared__ __align__(16) unsigned char smem[32256];
    int bid = blockIdx.x;
    int t = threadIdx.x;

    if (bid < PRE_T) {
        // ---- transpose NCHW fp32 -> padded NHWC fp16 ----
        float (*tile)[66] = (float (*)[66])smem;   // [w][c], pad 66 (16.9 KB)
        int half = bid & 1;
        int h = (bid >> 1) & 127;
        int n = bid >> 8;
        int w0 = half * 64;
        int g = t >> 6, wl = t & 63;
        const float* xb = x + ((size_t)n * CIN) * HW + h * WD + w0;
        #pragma unroll
        for (int i = 0; i < 16; i++) {
            int cc = i * 4 + g;
            tile[wl][cc] = xb[(size_t)cc * HW + wl];
        }
        __syncthreads();
        size_t rowbase = (((size_t)n * WP + (h + 1)) * WP + (w0 + 1)) * CIN;
        #pragma unroll
        for (int i = 0; i < 8; i++) {
            int u = i * 256 + t;
            int ww = u >> 5;
            int cp = (u & 31) * 2;
            float2 v = *(const float2*)&tile[ww][cp];
            *(unsigned int*)&xp[rowbase + (size_t)ww * CIN + cp] = pack_f16(v.x, v.y);
        }
    } else if (bid < PRE_T + PRE_H) {
        // ---- halo zero ----
        int widx = (bid - PRE_T) * 256 + t;
        if (widx < HALO_W8) {
            int s = widx * 8;
            int n = s / HALO_PER_N;
            int v = s - n * HALO_PER_N;
            size_t nb = (size_t)n * WP * WP * CIN;
            size_t base;
            if (v < 8320) {
                base = nb + v;
            } else if (v < 16640) {
                base = nb + (size_t)129 * WP * CIN + (v - 8320);
            } else if (v < 24832) {
                int v2 = v - 16640; int h = 1 + (v2 >> 6); int c = v2 & 63;
                base = nb + (size_t)h * WP * CIN + c;
            } else {
                int v3 = v - 24832; int h = 1 + (v3 >> 6); int c = v3 & 63;
                base = nb + ((size_t)h * WP + 129) * CIN + c;
            }
            short8 z = {0, 0, 0, 0, 0, 0, 0, 0};
            *(short8*)&xp[base] = z;
        }
    } else if (bid < PRE_T + PRE_H + PRE_W) {
        // ---- main-GEMM A-frag prep (fp16 bits) ----
        int idx = (bid - PRE_T - PRE_H) * 256 + t;   // < WAM exactly
        int jj = idx & 7;
        int lane = (idx >> 3) & 63;
        int kk = (idx >> 9) % NKK;
        int mt = (idx >> 9) / NKK;
        int o = mt * 16 + (lane & 15);
        int rp = kk * 32 + (lane >> 4) * 8 + jj;
        int k = rp >> 6, c = rp & 63;
        mhi[idx] = f2h(weight[((size_t)o * CIN + c) * 9 + k]);
    } else {
        // ---- conv + params: thread = pixel; packed-fp16 conv, chunked fp32 accum ----
        unsigned int (*wsH)[14] = (unsigned int (*)[14])smem;   // [CK][14] half2 (32256 B)
        for (int e = t; e < CK * 14; e += 256) {
            int m = e % 14;
            int citap = e / 14;
            int ci = citap / 9, tap = citap - ci * 9;
            int j0 = 2 * m, j1 = 2 * m + 1;
            float w0 = (j0 < 18) ? w_off[((size_t)j0 * CIN + ci) * 9 + tap]
                                 : w_mask[((size_t)(j0 - 18) * CIN + ci) * 9 + tap];
            float w1;
            if (j1 < 18)      w1 = w_off[((size_t)j1 * CIN + ci) * 9 + tap];
            else if (j1 < 27) w1 = w_mask[((size_t)(j1 - 18) * CIN + ci) * 9 + tap];
            else              w1 = 0.f;
            wsH[citap][m] = pack_f16(w0, w1);
        }
        __syncthreads();

        int pix = (bid - (PRE_T + PRE_H + PRE_W)) * 256 + t;
        int n  = pix >> 14;
        int ho = (pix >> 7) & 127;
        int wo = pix & 127;

        int offs[9];
        bool oks[9];
        #pragma unroll
        for (int dy = 0; dy < 3; dy++) {
            int y = ho - 1 + dy;
            #pragma unroll
            for (int dx = 0; dx < 3; dx++) {
                int xx = wo - 1 + dx;
                bool ok = (y >= 0) && (y < HD) && (xx >= 0) && (xx < WD);
                oks[dy * 3 + dx] = ok;
                offs[dy * 3 + dx] = (ok ? y : 0) * WD + (ok ? xx : 0);
            }
        }

        float accf[27];
        #pragma unroll
        for (int j = 0; j < 27; j++) accf[j] = 0.f;

        const float* xn = x + (size_t)n * CIN * HW;
        #pragma unroll 1
        for (int cc = 0; cc < 4; cc++) {            // chunks of 16 ci: cap fp16 chains
            half2v acc2[14];
            #pragma unroll
            for (int m = 0; m < 14; m++) acc2[m] = (half2v)(_Float16)0.f;
            for (int ci = cc * 16; ci < cc * 16 + 16; ci++) {
                const float* xc = xn + (size_t)ci * HW;
                float v[9];
                #pragma unroll
                for (int tap = 0; tap < 9; tap++)
                    v[tap] = oks[tap] ? xc[offs[tap]] : 0.f;
                #pragma unroll
                for (int tap = 0; tap < 9; tap++) {
                    half2v vh = dup_h2(v[tap]);
                    const unsigned int* wrow = wsH[ci * 9 + tap];
                    #pragma unroll
                    for (int m = 0; m < 14; m++) {
                        half2v w; __builtin_memcpy(&w, &wrow[m], 4);
                        acc2[m] = vh * w + acc2[m];           // v_pk_fma_f16
                    }
                }
            }
            #pragma unroll
            for (int m = 0; m < 14; m++) {
                accf[2 * m] += (float)acc2[m][0];
                if (2 * m + 1 < 27) accf[2 * m + 1] += (float)acc2[m][1];
            }
        }
        #pragma unroll
        for (int j = 0; j < 18; j++) accf[j] += b_off[j];
        #pragma unroll
        for (int j = 0; j < 9; j++)  accf[18 + j] += b_mask[j];

        float mk[9];
        #pragma unroll
        for (int j = 0; j < 9; j++) mk[j] = 1.f / (1.f + expf(-accf[18 + j]));

        #pragma unroll
        for (int k = 0; k < 9; k++) {
            float oy = accf[2 * k] * mk[(2 * k) % 9];
            float ox = accf[2 * k + 1] * mk[(2 * k + 1) % 9];
            int ki = k / 3, kj = k - ki * 3;
            float py = (float)(ho - 1 + ki) + oy;
            float px = (float)(wo - 1 + kj) + ox;
            float y0f = floorf(py), x0f = floorf(px);
            float wy = py - y0f, wx = px - x0f;
            int y0 = (int)y0f, x0 = (int)x0f;
            int y0c = min(max(y0, 0), HD - 1);
            int y1c = min(max(y0 + 1, 0), HD - 1);
            int x0c = min(max(x0, 0), WD - 1);
            int x1c = min(max(x0 + 1, 0), WD - 1);
            bool vy0 = (y0 >= 0) && (y0 < HD);
            bool vy1 = (y0 + 1 >= 0) && (y0 + 1 < HD);
            bool vx0 = (x0 >= 0) && (x0 < WD);
            bool vx1 = (x0 + 1 >= 0) && (x0 + 1 < WD);
            unsigned int meta = (unsigned int)y0c | ((unsigned int)x0c << 7)
                | ((unsigned int)(y1c - y0c) << 14) | ((unsigned int)(x1c - x0c) << 15)
                | ((vy0 && vx0) ? 0x10000u : 0u) | ((vy0 && vx1) ? 0x20000u : 0u)
                | ((vy1 && vx0) ? 0x40000u : 0u) | ((vy1 && vx1) ? 0x80000u : 0u);
            size_t pi = (size_t)(n * K2 + k) * HW + ho * WD + wo;
            wyP[pi] = wy;
            wxP[pi] = wx;
            metaP[pi] = meta;
        }
    }
}

// ---------------- fused kernel: params-load + gather + GEMM, ONE barrier ----------------
// grid (WD/TP=4, HD, NB), block 256, 4 blocks/CU (36864 B LDS).
__global__ __launch_bounds__(256, 4) void fused_kernel(
    const unsigned short* __restrict__ xp,
    const short* __restrict__ waM_hi,
    const float* __restrict__ wyP, const float* __restrict__ wxP,
    const unsigned int* __restrict__ metaP,
    const float* __restrict__ bias,
    float* __restrict__ out)
{
    // B operand: 72 chunks x (32 p-slots x 8 jj) fp16, slot = (p + c2) & 31
    __shared__ __align__(16) short val_s[72 * 256];      // 36864 B

    int t = threadIdx.x;
    int wv = t >> 6;
    int lane = t & 63;
    int wo0 = blockIdx.x * TP;
    int ho  = blockIdx.y;
    int n   = blockIdx.z;
    const unsigned short* xpn = xp + (size_t)n * WP * WP * CIN;
    int p16 = lane & 15, quad = lane >> 4;

    // ---- stage-5 A prefetch: kk 0..7, independent of the gather ----
    half8 apre[8];
    #pragma unroll
    for (int kk = 0; kk < 8; kk++)
        apre[kk] = *(const half8*)&waM_hi[((wv * NKK + kk) * 64 + lane) * 8];

    // ---- gather: thread owns pixel p = t>>3, group g = t&7; k = iter ----
    {
        int p = t >> 3, g = t & 7, c0 = g * 8;
        size_t pbase = (size_t)(n * K2) * HW + (size_t)ho * WD + wo0 + p;
        #pragma unroll
        for (int i = 0; i < 9; i++) {
            size_t pi = pbase + (size_t)i * HW;
            float wy = wyP[pi];
            float wx = wxP[pi];
            unsigned int m = metaP[pi];
            float wy0 = 1.f - wy, wx0 = 1.f - wx;
            float wA = (m & 0x10000u) ? wy0 * wx0 : 0.f;
            float wB = (m & 0x20000u) ? wy0 * wx  : 0.f;
            float wC = (m & 0x40000u) ? wy  * wx0 : 0.f;
            float wD = (m & 0x80000u) ? wy  * wx  : 0.f;
            half2v wa2 = dup_h2(wA), wb2 = dup_h2(wB), wc2 = dup_h2(wC), wd2 = dup_h2(wD);
            int y0c = (int)(m & 127u);
            int x0c = (int)((m >> 7) & 127u);
            int ry0 = (y0c + 1) * (WP * CIN);
            int ry1 = ry0 + (int)((m >> 14) & 1u) * (WP * CIN);
            int cx0 = (x0c + 1) * CIN + c0;
            int cx1 = (x0c + 1) * CIN + (int)((m >> 15) & 1u) * CIN + c0;
            uint4 qa = *(const uint4*)&xpn[ry0 + cx0];
            uint4 qb = *(const uint4*)&xpn[ry0 + cx1];
            uint4 qc = *(const uint4*)&xpn[ry1 + cx0];
            uint4 qd = *(const uint4*)&xpn[ry1 + cx1];
            unsigned int qa_[4] = {qa.x, qa.y, qa.z, qa.w};
            unsigned int qb_[4] = {qb.x, qb.y, qb.z, qb.w};
            unsigned int qc_[4] = {qc.x, qc.y, qc.z, qc.w};
            unsigned int qd_[4] = {qd.x, qd.y, qd.z, qd.w};
            unsigned int r_[4];
            #pragma unroll
            for (int d = 0; d < 4; d++) {
                half2v ha, hb, hc, hd;
                __builtin_memcpy(&ha, &qa_[d], 4);
                __builtin_memcpy(&hb, &qb_[d], 4);
                __builtin_memcpy(&hc, &qc_[d], 4);
                __builtin_memcpy(&hd, &qd_[d], 4);
                half2v gg = wa2 * ha + wb2 * hb + wc2 * hc + wd2 * hd;   // 4x v_pk_fma_f16
                __builtin_memcpy(&r_[d], &gg, 4);
            }
            uint4 r = {r_[0], r_[1], r_[2], r_[3]};
            int c2 = i * 8 + g;
            *(uint4*)&val_s[c2 * 256 + ((p + c2) & 31) * 8] = r;
        }
    }
    __syncthreads();

    // ---- main GEMM C[64 o][32 p] (fp16 MFMA); kk 0..7 A from prefetch regs ----
    f32x4 a0 = {0.f, 0.f, 0.f, 0.f};
    f32x4 a1 = {0.f, 0.f, 0.f, 0.f};
    #pragma unroll
    for (int kk = 0; kk < NKK; kk++) {
        half8 ah;
        if (kk < 8) ah = apre[kk];
        else        ah = *(const half8*)&waM_hi[((wv * NKK + kk) * 64 + lane) * 8];
        int c2 = kk * 4 + quad;
        half8 b0 = *(const half8*)&val_s[c2 * 256 + ((p16 + c2) & 31) * 8];
        half8 b1 = *(const half8*)&val_s[c2 * 256 + ((16 + p16 + c2) & 31) * 8];
        a0 = __builtin_amdgcn_mfma_f32_16x16x32_f16(ah, b0, a0, 0, 0, 0);
        a1 = __builtin_amdgcn_mfma_f32_16x16x32_f16(ah, b1, a1, 0, 0, 0);
    }

    // ---- epilogue: direct stores ----
    size_t obase = ((size_t)n * COUT) * HW + (size_t)ho * WD + wo0;
    #pragma unroll
    for (int i = 0; i < 4; i++) {
        int o = wv * 16 + quad * 4 + i;
        float bv = bias[o];
        out[obase + (size_t)o * HW + p16] = a0[i] + bv;
        out[obase + (size_t)o * HW + 16 + p16] = a1[i] + bv;
    }
}

// ================= fallback path (R1-proven, fp32 NCHW, TPF=16) =================
__global__ void transpose_w_kernel(const float* __restrict__ w, float* __restrict__ wt) {
    int i = blockIdx.x * 256 + threadIdx.x;
    int o = i / CK;
    int ck = i - o * CK;
    wt[ck * COUT + o] = w[i];
}

__global__ __launch_bounds__(256) void offmask_kernel(
    const float* __restrict__ x,
    const float* __restrict__ w_off, const float* __restrict__ b_off,
    const float* __restrict__ w_mask, const float* __restrict__ b_mask,
    float* __restrict__ offy, float* __restrict__ offx)
{
    __shared__ float ws[CK][27];
    int t = threadIdx.x;
    for (int i = t; i < CK * 27; i += 256) {
        int j = i % 27;
        int citap = i / 27;
        int ci = citap / 9;
        int tap = citap - ci * 9;
        float v;
        if (j < 18) v = w_off[(j * CIN + ci) * 9 + tap];
        else        v = w_mask[((j - 18) * CIN + ci) * 9 + tap];
        ws[citap][j] = v;
    }
    __syncthreads();

    int pix = blockIdx.x * 256 + t;
    int n  = pix >> 14;
    int ho = (pix >> 7) & 127;
    int wo = pix & 127;

    float acc[27];
    #pragma unroll
    for (int j = 0; j < 18; j++) acc[j] = b_off[j];
    #pragma unroll
    for (int j = 0; j < 9; j++)  acc[18 + j] = b_mask[j];

    int offs[9];
    bool oks[9];
    #pragma unroll
    for (int dy = 0; dy < 3; dy++) {
        int y = ho - 1 + dy;
        #pragma unroll
        for (int dx = 0; dx < 3; dx++) {
            int xx = wo - 1 + dx;
            bool ok = (y >= 0) && (y < HD) && (xx >= 0) && (xx < WD);
            oks[dy * 3 + dx] = ok;
            offs[dy * 3 + dx] = (ok ? y : 0) * WD + (ok ? xx : 0);
        }
    }
    const float* xn = x + (size_t)n * CIN * HW;
    for (int ci = 0; ci < CIN; ci++) {
        const float* xc = xn + (size_t)ci * HW;
        float v[9];
        #pragma unroll
        for (int tap = 0; tap < 9; tap++)
            v[tap] = oks[tap] ? xc[offs[tap]] : 0.f;
        #pragma unroll
        for (int tap = 0; tap < 9; tap++) {
            const float* wrow = ws[ci * 9 + tap];
            float vv = v[tap];
            #pragma unroll
            for (int j = 0; j < 27; j++) acc[j] += wrow[j] * vv;
        }
    }
    float m[9];
    #pragma unroll
    for (int j = 0; j < 9; j++) m[j] = 1.f / (1.f + expf(-acc[18 + j]));
    #pragma unroll
    for (int k = 0; k < 9; k++) {
        int cy = 2 * k, cx = 2 * k + 1;
        float my = m[cy < 9 ? cy : cy - 9];
        float mx = m[cx < 9 ? cx : cx - 9];
        size_t o = (((size_t)n * K2 + k) * HD + ho) * WD + wo;
        offy[o] = acc[cy] * my;
        offx[o] = acc[cx] * mx;
    }
}

__global__ __launch_bounds__(256) void deform_kernel(
    const float* __restrict__ x,
    const float* __restrict__ offy, const float* __restrict__ offx,
    const float* __restrict__ wt,
    const float* __restrict__ bias,
    float* __restrict__ out)
{
    __shared__ __align__(16) float val_f[CK * TPF];
    __shared__ float4 p_w4[K2 * TPF];
    __shared__ int4   p_idx4[K2 * TPF];

    int t = threadIdx.x;
    int wo0 = blockIdx.x * TPF;
    int ho  = blockIdx.y;
    int n   = blockIdx.z;

    if (t < K2 * TPF) {
        int k = t >> 4, p = t & 15;
        int wo = wo0 + p;
        size_t oi = (((size_t)n * K2 + k) * HD + ho) * WD + wo;
        float oy = offy[oi], ox = offx[oi];
        int ki = k / 3, kj = k - ki * 3;
        float py = (float)(ho - 1 + ki) + oy;
        float px = (float)(wo - 1 + kj) + ox;
        float y0f = floorf(py), x0f = floorf(px);
        float wy = py - y0f, wx = px - x0f;
        int y0 = (int)y0f, x0 = (int)x0f;
        float wy0 = 1.f - wy, wx0 = 1.f - wx;
        int y0c = min(max(y0, 0), HD - 1);
        int y1c = min(max(y0 + 1, 0), HD - 1);
        int x0c = min(max(x0, 0), WD - 1);
        int x1c = min(max(x0 + 1, 0), WD - 1);
        bool vy0 = (y0 >= 0) && (y0 < HD);
        bool vy1 = (y0 + 1 >= 0) && (y0 + 1 < HD);
        bool vx0 = (x0 >= 0) && (x0 < WD);
        bool vx1 = (x0 + 1 >= 0) && (x0 + 1 < WD);
        float4 w4;
        w4.x = (vy0 && vx0) ? wy0 * wx0 : 0.f;
        w4.y = (vy0 && vx1) ? wy0 * wx  : 0.f;
        w4.z = (vy1 && vx0) ? wy  * wx0 : 0.f;
        w4.w = (vy1 && vx1) ? wy  * wx  : 0.f;
        int4 i4;
        i4.x = y0c * WD + x0c;
        i4.y = y0c * WD + x1c;
        i4.z = y1c * WD + x0c;
        i4.w = y1c * WD + x1c;
        p_w4[t] = w4;
        p_idx4[t] = i4;
    }
    __syncthreads();

    const float* xn = x + (size_t)n * CIN * HW;
    for (int e = t; e < CK * TPF; e += 256) {
        int row = e >> 4, p = e & 15;
        int cc = row / 9, k = row - cc * 9;
        int task = (k << 4) | p;
        float4 w4 = p_w4[task];
        int4  i4 = p_idx4[task];
        const float* xc = xn + (size_t)cc * HW;
        val_f[e] = w4.x * xc[i4.x] + w4.y * xc[i4.y]
                 + w4.z * xc[i4.z] + w4.w * xc[i4.w];
    }
    __syncthreads();

    int o = t & 63, q = t >> 6;
    float4 acc = {0.f, 0.f, 0.f, 0.f};
    const float4* v4 = (const float4*)val_f;
    const float* wp = wt + o;
    #pragma unroll 4
    for (int r = 0; r < CK; r++) {
        float w = wp[r * COUT];
        float4 vv = v4[r * 4 + q];
        acc.x += w * vv.x; acc.y += w * vv.y;
        acc.z += w * vv.z; acc.w += w * vv.w;
    }
    float b = bias[o];
    acc.x += b; acc.y += b; acc.z += b; acc.w += b;
    __syncthreads();
    float4* o4 = (float4*)val_f;
    o4[o * 4 + q] = acc;
    __syncthreads();
    size_t obase = ((size_t)n * COUT) * HW + (size_t)ho * WD + wo0;
    #pragma unroll
    for (int i = 0; i < 4; i++) {
        int l = t + 256 * i;
        int oo = l >> 4, p = l & 15;
        out[obase + (size_t)oo * HW + p] = val_f[l];
    }
}

extern "C" void kernel_launch(void* const* d_in, const int* in_sizes, int n_in,
                              void* d_out, int out_size, void* d_ws, size_t ws_size,
                              hipStream_t stream) {
    const float* x      = (const float*)d_in[0];
    const float* w_off  = (const float*)d_in[1];
    const float* b_off  = (const float*)d_in[2];
    const float* w_mask = (const float*)d_in[3];
    const float* b_mask = (const float*)d_in[4];
    const float* weight = (const float*)d_in[5];
    const float* bias   = (const float*)d_in[6];
    float* out = (float*)d_out;

    // ws layout: waM (shorts) | xp (ushorts) | wyP (f32) | wxP (f32) | metaP (u32)
    short* waM_hi = (short*)d_ws;
    unsigned short* xp = (unsigned short*)(waM_hi + WAM);
    float* wyP = (float*)(xp + XTP);
    float* wxP = wyP + OFFSZ;
    unsigned int* metaP = (unsigned int*)(wxP + OFFSZ);
    size_t need = (size_t)WAM * 2 + XTP * 2 + OFFSZ * 12;

    if (ws_size >= need) {
        pre_kernel<<<PRE_T + PRE_H + PRE_W + PRE_C, 256, 0, stream>>>(
            x, weight, w_off, b_off, w_mask, b_mask, xp, waM_hi, wyP, wxP, metaP);
        fused_kernel<<<dim3(WD / TP, HD, NB), 256, 0, stream>>>(
            xp, waM_hi, wyP, wxP, metaP, bias, out);
    } else {
        float* offy = (float*)d_ws;
        float* offx = offy + OFFSZ;
        float* wt   = offx + OFFSZ;
        transpose_w_kernel<<<144, 256, 0, stream>>>(weight, wt);
        offmask_kernel<<<256, 256, 0, stream>>>(x, w_off, b_off, w_mask, b_mask, offy, offx);
        deform_kernel<<<dim3(WD / TPF, HD, NB), 256, 0, stream>>>(x, offy, offx, wt, bias, out);
    }
}

// Round 9
// 118.295 us; speedup vs baseline: 1.6183x; 1.6183x over previous
//
#include <hip/hip_runtime.h>
#include <math.h>

#define HD 128
#define WD 128
#define WP 130              // padded width/height (1-halo)
#define CIN 64
#define COUT 64
#define NB 4
#define K2 9
#define HW (HD*WD)          // 16384
#define CK 576              // CIN*K2, K of both GEMMs (k-major permuted: r' = k*64+c)
#define TP 32               // pixels per block (fused kernel)
#define TPF 16              // pixels per block (fallback kernel)
#define NKK 18              // K-steps of 32
#define WR 6                // window rows  (image y in [ho-2, ho+3])
#define WC 36               // window cols  (image x in [wo0-2, wo0+33])

#define WAM   (4 * NKK * 64 * 8)             // 36864 shorts main A-frag buffer (fp16 bits)
#define WAO   (2 * NKK * 64 * 8)             // 18432 shorts offset A-frag buffer (fp16 bits)
#define XTP   ((size_t)NB * WP * WP * CIN)   // 4326400 shorts (padded NHWC fp16 x)
#define OFFSZ ((size_t)NB * K2 * HW)         // fallback
#define WTSZ  ((size_t)CK * COUT)            // fallback

// pre_kernel block partition
#define PRE_T 1024                            // transpose blocks
#define PRE_H 65                              // halo-zero blocks
#define PRE_P ((WAM + WAO) / 256)             // 216 prep blocks
#define HALO_PER_N 33024                      // halo shorts per image
#define HALO_W8 16512                         // total 8-short zero units

typedef __attribute__((ext_vector_type(8))) short short8;
typedef __attribute__((ext_vector_type(4))) float f32x4;
typedef _Float16 half8 __attribute__((ext_vector_type(8)));
typedef _Float16 half2v __attribute__((ext_vector_type(2)));

// fp32 -> fp16 bits (scalar, RTN)
__device__ inline short f2h(float v) {
    _Float16 h = (_Float16)v;
    short s; __builtin_memcpy(&s, &h, 2); return s;
}
// pack two fp32 -> dword of two fp16 (v_cvt_pkrtz_f16_f32, 1 instr)
__device__ inline unsigned int pack_f16(float a, float b) {
    auto h = __builtin_amdgcn_cvt_pkrtz(a, b);
    unsigned int u; __builtin_memcpy(&u, &h, 4); return u;
}
// duplicate one fp32 into both halves of a packed fp16 pair
__device__ inline half2v dup_h2(float a) {
    auto h = __builtin_amdgcn_cvt_pkrtz(a, a);
    half2v r; __builtin_memcpy(&r, &h, 4); return r;
}

// ---------------- merged pre-kernel: transpose | halo zero | weight prep ----------------
__global__ __launch_bounds__(256) void pre_kernel(
    const float* __restrict__ x,
    const float* __restrict__ weight,
    const float* __restrict__ w_off,
    const float* __restrict__ w_mask,
    unsigned short* __restrict__ xp,
    short* __restrict__ mhi, short* __restrict__ ohi)
{
    __shared__ float tile[64][66];   // [w][c], pad 66
    int bid = blockIdx.x;
    int t = threadIdx.x;

    if (bid < PRE_T) {
        int half = bid & 1;
        int h = (bid >> 1) & 127;
        int n = bid >> 8;
        int w0 = half * 64;
        int g = t >> 6, wl = t & 63;
        const float* xb = x + ((size_t)n * CIN) * HW + h * WD + w0;
        #pragma unroll
        for (int i = 0; i < 16; i++) {
            int cc = i * 4 + g;
            tile[wl][cc] = xb[(size_t)cc * HW + wl];
        }
        __syncthreads();
        size_t rowbase = (((size_t)n * WP + (h + 1)) * WP + (w0 + 1)) * CIN;
        #pragma unroll
        for (int i = 0; i < 8; i++) {
            int u = i * 256 + t;
            int ww = u >> 5;
            int cp = (u & 31) * 2;
            float2 v = *(const float2*)&tile[ww][cp];
            *(unsigned int*)&xp[rowbase + (size_t)ww * CIN + cp] = pack_f16(v.x, v.y);
        }
    } else if (bid < PRE_T + PRE_H) {
        int widx = (bid - PRE_T) * 256 + t;
        if (widx < HALO_W8) {
            int s = widx * 8;
            int n = s / HALO_PER_N;
            int v = s - n * HALO_PER_N;
            size_t nb = (size_t)n * WP * WP * CIN;
            size_t base;
            if (v < 8320) {
                base = nb + v;
            } else if (v < 16640) {
                base = nb + (size_t)129 * WP * CIN + (v - 8320);
            } else if (v < 24832) {
                int v2 = v - 16640; int h = 1 + (v2 >> 6); int c = v2 & 63;
                base = nb + (size_t)h * WP * CIN + c;
            } else {
                int v3 = v - 24832; int h = 1 + (v3 >> 6); int c = v3 & 63;
                base = nb + ((size_t)h * WP + 129) * CIN + c;
            }
            short8 z = {0, 0, 0, 0, 0, 0, 0, 0};
            *(short8*)&xp[base] = z;
        }
    } else {
        int gid = (bid - PRE_T - PRE_H) * 256 + t;
        if (gid < WAM) {
            int idx = gid;
            int jj = idx & 7;
            int lane = (idx >> 3) & 63;
            int kk = (idx >> 9) % NKK;
            int mt = (idx >> 9) / NKK;
            int o = mt * 16 + (lane & 15);
            int rp = kk * 32 + (lane >> 4) * 8 + jj;
            int k = rp >> 6, c = rp & 63;
            mhi[idx] = f2h(weight[((size_t)o * CIN + c) * 9 + k]);
        } else {
            int idx = gid - WAM;
            int jj = idx & 7;
            int lane = (idx >> 3) & 63;
            int kk = (idx >> 9) % NKK;
            int mt = (idx >> 9) / NKK;
            int j = mt * 16 + (lane & 15);
            int rp = kk * 32 + (lane >> 4) * 8 + jj;
            int k = rp >> 6, c = rp & 63;
            float w = 0.f;
            if (j < 18)      w = w_off[((size_t)j * CIN + c) * 9 + k];
            else if (j < 27) w = w_mask[((size_t)(j - 18) * CIN + c) * 9 + k];
            ohi[idx] = f2h(w);
        }
    }
}

// window LDS address (in shorts): slot (r,c), channel group g, rotation (g+c)&7
#define WIN_ADDR(r, c, g) ((((r) * WC + (c)) * 8 + (((g) + (c)) & 7)) * 8)

// ---------------- fused kernel, TP=32, fp16, LDS-window gather ----------------
// grid (WD/TP=4, HD, NB), block 256, 2 blocks/CU (67968 B LDS).
// LDS: window 6x36x64 fp16 (27648 B) + 72-chunk B buffer (36864 B) + U (3456 B).
// Window holds xp rows (ho-1+r), cols (wo0-1+c) clamped to [0,129]:
//   conv B-frags AND all bilinear corners read from it (global fallback per task).
__global__ __launch_bounds__(256, 2) void fused_kernel(
    const unsigned short* __restrict__ xp,
    const short* __restrict__ waM_hi,
    const short* __restrict__ waO_hi,
    const float* __restrict__ b_off, const float* __restrict__ b_mask,
    const float* __restrict__ bias,
    float* __restrict__ out)
{
    __shared__ __align__(16) short win_s[WR * WC * 64];  // 27648 B
    __shared__ __align__(16) short val_s[72 * 256];      // 36864 B, slot = (p + c2) & 31
    __shared__ __align__(16) float U[27 * 32];           // 3456 B union region

    int t = threadIdx.x;
    int wv = t >> 6;
    int lane = t & 63;
    int wo0 = blockIdx.x * TP;
    int ho  = blockIdx.y;
    int n   = blockIdx.z;
    const unsigned short* xpn = xp + (size_t)n * WP * WP * CIN;
    int p16 = lane & 15, quad = lane >> 4;

    // ---- stage-5 A prefetch: kk 0..5, independent of all phases ----
    half8 apre[6];
    #pragma unroll
    for (int kk = 0; kk < 6; kk++)
        apre[kk] = *(const half8*)&waM_hi[((wv * NKK + kk) * 64 + lane) * 8];

    // ---- stage W: coalesced window load, 1728 16B units ----
    #pragma unroll
    for (int i = 0; i < 7; i++) {
        int u = t + 256 * i;
        if (u < WR * WC * 8) {
            int s = u >> 3, g = u & 7;
            int r = s / WC, c = s - r * WC;
            int yr = min(max(ho - 1 + r, 0), 129);
            int xc = min(max(wo0 - 1 + c, 0), 129);
            const short8 v = *(const short8*)&xpn[((size_t)yr * WP + xc) * CIN + g * 8];
            *(short8*)&win_s[WIN_ADDR(r, c, g)] = v;
        }
    }
    __syncthreads();

    // ---- stage 2: offset/mask conv GEMM on waves 0-1; B-frags straight from window ----
    if (wv < 2) {
        int jt = wv;
        f32x4 c0a = {0.f, 0.f, 0.f, 0.f};
        f32x4 c1a = {0.f, 0.f, 0.f, 0.f};
        #pragma unroll
        for (int kk = 0; kk < NKK; kk++) {
            int abase = ((jt * NKK + kk) * 64 + lane) * 8;
            half8 ah = *(const half8*)&waO_hi[abase];
            const int tap = kk >> 1;            // compile-time
            const int ti = tap / 3;             // compile-time
            const int tj = tap - ti * 3;        // compile-time
            int gg = (kk & 1) * 4 + quad;
            int r = ti + 1;
            int ca = p16 + tj + 1;
            int cb = 16 + p16 + tj + 1;
            half8 b0 = *(const half8*)&win_s[WIN_ADDR(r, ca, gg)];
            half8 b1 = *(const half8*)&win_s[WIN_ADDR(r, cb, gg)];
            c0a = __builtin_amdgcn_mfma_f32_16x16x32_f16(ah, b0, c0a, 0, 0, 0);
            c1a = __builtin_amdgcn_mfma_f32_16x16x32_f16(ah, b1, c1a, 0, 0, 0);
        }
        #pragma unroll
        for (int i = 0; i < 4; i++) {
            int j = jt * 16 + quad * 4 + i;
            if (j < 27) {
                float bv = (j < 18) ? b_off[j] : b_mask[j - 18];
                U[j * 32 + p16] = c0a[i] + bv;
                U[j * 32 + 16 + p16] = c1a[i] + bv;
            }
        }
    }
    __syncthreads();

    // ---- stage 3: sigmoid-modulated offsets -> compressed bilinear params + inW bit ----
    float rwy[2], rwx[2];
    unsigned int rmeta[2];
    #pragma unroll
    for (int pass = 0; pass < 2; pass++) {
        int u = t + pass * 256;
        if (u < K2 * TP) {
            int k = u >> 5, p = u & 31;
            float oy_raw = U[(2 * k) * 32 + p];
            float ox_raw = U[(2 * k + 1) * 32 + p];
            float my = 1.f / (1.f + expf(-U[(18 + (2 * k) % 9) * 32 + p]));
            float mx = 1.f / (1.f + expf(-U[(18 + (2 * k + 1) % 9) * 32 + p]));
            float oy = oy_raw * my;
            float ox = ox_raw * mx;
            int ki = k / 3, kj = k - ki * 3;
            int wo = wo0 + p;
            float py = (float)(ho - 1 + ki) + oy;
            float px = (float)(wo - 1 + kj) + ox;
            float y0f = floorf(py), x0f = floorf(px);
            float wy = py - y0f, wx = px - x0f;
            int y0 = (int)y0f, x0 = (int)x0f;
            int y0c = min(max(y0, 0), HD - 1);
            int y1c = min(max(y0 + 1, 0), HD - 1);
            int x0c = min(max(x0, 0), WD - 1);
            int x1c = min(max(x0 + 1, 0), WD - 1);
            bool vy0 = (y0 >= 0) && (y0 < HD);
            bool vy1 = (y0 + 1 >= 0) && (y0 + 1 < HD);
            bool vx0 = (x0 >= 0) && (x0 < WD);
            bool vx1 = (x0 + 1 >= 0) && (x0 + 1 < WD);
            // in-window test (clamped coords vs window extent)
            bool inW = (y0c >= ho - 2) && (y1c <= ho + 3)
                    && (x0c >= wo0 - 2) && (x1c <= wo0 + 33);
            rwy[pass] = wy;
            rwx[pass] = wx;
            rmeta[pass] = (unsigned int)y0c | ((unsigned int)x0c << 7)
                        | ((unsigned int)(y1c - y0c) << 14) | ((unsigned int)(x1c - x0c) << 15)
                        | ((vy0 && vx0) ? 0x10000u : 0u) | ((vy0 && vx1) ? 0x20000u : 0u)
                        | ((vy1 && vx0) ? 0x40000u : 0u) | ((vy1 && vx1) ? 0x80000u : 0u)
                        | (inW ? 0x100000u : 0u);
        }
    }
    __syncthreads();
    #pragma unroll
    for (int pass = 0; pass < 2; pass++) {
        int u = t + pass * 256;
        if (u < K2 * TP) {
            U[u] = rwy[pass];
            U[288 + u] = rwx[pass];
            ((unsigned int*)U)[576 + u] = rmeta[pass];
        }
    }
    __syncthreads();

    // ---- stage 4: bilinear gather FROM LDS WINDOW (global fallback per task) ----
    // unit u = task*8 + g ; 288 tasks x 8 groups = 2304 units, 9 exact iters
    #pragma unroll
    for (int i = 0; i < 9; i++) {
        int u = t + 256 * i;
        int task = u >> 3;
        int g = u & 7;
        int c0 = g * 8;
        int k = task >> 5, p = task & 31;
        float wy = U[task];
        float wx = U[288 + task];
        unsigned int m = ((const unsigned int*)U)[576 + task];
        float wy0 = 1.f - wy, wx0 = 1.f - wx;
        float wA = (m & 0x10000u) ? wy0 * wx0 : 0.f;
        float wB = (m & 0x20000u) ? wy0 * wx  : 0.f;
        float wC = (m & 0x40000u) ? wy  * wx0 : 0.f;
        float wD = (m & 0x80000u) ? wy  * wx  : 0.f;
        half2v wa2 = dup_h2(wA), wb2 = dup_h2(wB), wc2 = dup_h2(wC), wd2 = dup_h2(wD);
        int y0c = (int)(m & 127u);
        int x0c = (int)((m >> 7) & 127u);
        int dy1 = (int)((m >> 14) & 1u);
        int dx1 = (int)((m >> 15) & 1u);
        uint4 qa, qb, qc, qd;
        if (m & 0x100000u) {
            int r0 = y0c - (ho - 2);
            int r1 = r0 + dy1;
            int cA = x0c - (wo0 - 2);
            int cB = cA + dx1;
            qa = *(const uint4*)&win_s[WIN_ADDR(r0, cA, g)];
            qb = *(const uint4*)&win_s[WIN_ADDR(r0, cB, g)];
            qc = *(const uint4*)&win_s[WIN_ADDR(r1, cA, g)];
            qd = *(const uint4*)&win_s[WIN_ADDR(r1, cB, g)];
        } else {
            int ry0 = (y0c + 1) * (WP * CIN);
            int ry1 = ry0 + dy1 * (WP * CIN);
            int cx0 = (x0c + 1) * CIN + c0;
            int cx1 = (x0c + 1) * CIN + dx1 * CIN + c0;
            qa = *(const uint4*)&xpn[ry0 + cx0];
            qb = *(const uint4*)&xpn[ry0 + cx1];
            qc = *(const uint4*)&xpn[ry1 + cx0];
            qd = *(const uint4*)&xpn[ry1 + cx1];
        }
        unsigned int qa_[4] = {qa.x, qa.y, qa.z, qa.w};
        unsigned int qb_[4] = {qb.x, qb.y, qb.z, qb.w};
        unsigned int qc_[4] = {qc.x, qc.y, qc.z, qc.w};
        unsigned int qd_[4] = {qd.x, qd.y, qd.z, qd.w};
        unsigned int r_[4];
        #pragma unroll
        for (int d = 0; d < 4; d++) {
            half2v ha, hb, hc, hd;
            __builtin_memcpy(&ha, &qa_[d], 4);
            __builtin_memcpy(&hb, &qb_[d], 4);
            __builtin_memcpy(&hc, &qc_[d], 4);
            __builtin_memcpy(&hd, &qd_[d], 4);
            half2v gg = wa2 * ha + wb2 * hb + wc2 * hc + wd2 * hd;   // 4x v_pk_fma_f16
            __builtin_memcpy(&r_[d], &gg, 4);
        }
        uint4 r = {r_[0], r_[1], r_[2], r_[3]};
        int c2 = k * 8 + g;
        *(uint4*)&val_s[c2 * 256 + ((p + c2) & 31) * 8] = r;
    }
    __syncthreads();

    // ---- stage 5: main GEMM C[64 o][32 p] (fp16 MFMA); kk 0..5 A from prefetch regs ----
    f32x4 a0 = {0.f, 0.f, 0.f, 0.f};
    f32x4 a1 = {0.f, 0.f, 0.f, 0.f};
    #pragma unroll
    for (int kk = 0; kk < NKK; kk++) {
        half8 ah;
        if (kk < 6) ah = apre[kk];
        else        ah = *(const half8*)&waM_hi[((wv * NKK + kk) * 64 + lane) * 8];
        int c2 = kk * 4 + quad;
        half8 b0 = *(const half8*)&val_s[c2 * 256 + ((p16 + c2) & 31) * 8];
        half8 b1 = *(const half8*)&val_s[c2 * 256 + ((16 + p16 + c2) & 31) * 8];
        a0 = __builtin_amdgcn_mfma_f32_16x16x32_f16(ah, b0, a0, 0, 0, 0);
        a1 = __builtin_amdgcn_mfma_f32_16x16x32_f16(ah, b1, a1, 0, 0, 0);
    }

    // ---- epilogue: direct stores ----
    size_t obase = ((size_t)n * COUT) * HW + (size_t)ho * WD + wo0;
    #pragma unroll
    for (int i = 0; i < 4; i++) {
        int o = wv * 16 + quad * 4 + i;
        float bv = bias[o];
        out[obase + (size_t)o * HW + p16] = a0[i] + bv;
        out[obase + (size_t)o * HW + 16 + p16] = a1[i] + bv;
    }
}

// ================= fallback path (R1-proven, fp32 NCHW, TPF=16) =================
__global__ void transpose_w_kernel(const float* __restrict__ w, float* __restrict__ wt) {
    int i = blockIdx.x * 256 + threadIdx.x;
    int o = i / CK;
    int ck = i - o * CK;
    wt[ck * COUT + o] = w[i];
}

__global__ __launch_bounds__(256) void offmask_kernel(
    const float* __restrict__ x,
    const float* __restrict__ w_off, const float* __restrict__ b_off,
    const float* __restrict__ w_mask, const float* __restrict__ b_mask,
    float* __restrict__ offy, float* __restrict__ offx)
{
    __shared__ float ws[CK][27];
    int t = threadIdx.x;
    for (int i = t; i < CK * 27; i += 256) {
        int j = i % 27;
        int citap = i / 27;
        int ci = citap / 9;
        int tap = citap - ci * 9;
        float v;
        if (j < 18) v = w_off[(j * CIN + ci) * 9 + tap];
        else        v = w_mask[((j - 18) * CIN + ci) * 9 + tap];
        ws[citap][j] = v;
    }
    __syncthreads();

    int pix = blockIdx.x * 256 + t;
    int n  = pix >> 14;
    int ho = (pix >> 7) & 127;
    int wo = pix & 127;

    float acc[27];
    #pragma unroll
    for (int j = 0; j < 18; j++) acc[j] = b_off[j];
    #pragma unroll
    for (int j = 0; j < 9; j++)  acc[18 + j] = b_mask[j];

    int offs[9];
    bool oks[9];
    #pragma unroll
    for (int dy = 0; dy < 3; dy++) {
        int y = ho - 1 + dy;
        #pragma unroll
        for (int dx = 0; dx < 3; dx++) {
            int xx = wo - 1 + dx;
            bool ok = (y >= 0) && (y < HD) && (xx >= 0) && (xx < WD);
            oks[dy * 3 + dx] = ok;
            offs[dy * 3 + dx] = (ok ? y : 0) * WD + (ok ? xx : 0);
        }
    }
    const float* xn = x + (size_t)n * CIN * HW;
    for (int ci = 0; ci < CIN; ci++) {
        const float* xc = xn + (size_t)ci * HW;
        float v[9];
        #pragma unroll
        for (int tap = 0; tap < 9; tap++)
            v[tap] = oks[tap] ? xc[offs[tap]] : 0.f;
        #pragma unroll
        for (int tap = 0; tap < 9; tap++) {
            const float* wrow = ws[ci * 9 + tap];
            float vv = v[tap];
            #pragma unroll
            for (int j = 0; j < 27; j++) acc[j] += wrow[j] * vv;
        }
    }
    float m[9];
    #pragma unroll
    for (int j = 0; j < 9; j++) m[j] = 1.f / (1.f + expf(-acc[18 + j]));
    #pragma unroll
    for (int k = 0; k < 9; k++) {
        int cy = 2 * k, cx = 2 * k + 1;
        float my = m[cy < 9 ? cy : cy - 9];
        float mx = m[cx < 9 ? cx : cx - 9];
        size_t o = (((size_t)n * K2 + k) * HD + ho) * WD + wo;
        offy[o] = acc[cy] * my;
        offx[o] = acc[cx] * mx;
    }
}

__global__ __launch_bounds__(256) void deform_kernel(
    const float* __restrict__ x,
    const float* __restrict__ offy, const float* __restrict__ offx,
    const float* __restrict__ wt,
    const float* __restrict__ bias,
    float* __restrict__ out)
{
    __shared__ __align__(16) float val_f[CK * TPF];
    __shared__ float4 p_w4[K2 * TPF];
    __shared__ int4   p_idx4[K2 * TPF];

    int t = threadIdx.x;
    int wo0 = blockIdx.x * TPF;
    int ho  = blockIdx.y;
    int n   = blockIdx.z;

    if (t < K2 * TPF) {
        int k = t >> 4, p = t & 15;
        int wo = wo0 + p;
        size_t oi = (((size_t)n * K2 + k) * HD + ho) * WD + wo;
        float oy = offy[oi], ox = offx[oi];
        int ki = k / 3, kj = k - ki * 3;
        float py = (float)(ho - 1 + ki) + oy;
        float px = (float)(wo - 1 + kj) + ox;
        float y0f = floorf(py), x0f = floorf(px);
        float wy = py - y0f, wx = px - x0f;
        int y0 = (int)y0f, x0 = (int)x0f;
        float wy0 = 1.f - wy, wx0 = 1.f - wx;
        int y0c = min(max(y0, 0), HD - 1);
        int y1c = min(max(y0 + 1, 0), HD - 1);
        int x0c = min(max(x0, 0), WD - 1);
        int x1c = min(max(x0 + 1, 0), WD - 1);
        bool vy0 = (y0 >= 0) && (y0 < HD);
        bool vy1 = (y0 + 1 >= 0) && (y0 + 1 < HD);
        bool vx0 = (x0 >= 0) && (x0 < WD);
        bool vx1 = (x0 + 1 >= 0) && (x0 + 1 < WD);
        float4 w4;
        w4.x = (vy0 && vx0) ? wy0 * wx0 : 0.f;
        w4.y = (vy0 && vx1) ? wy0 * wx  : 0.f;
        w4.z = (vy1 && vx0) ? wy  * wx0 : 0.f;
        w4.w = (vy1 && vx1) ? wy  * wx  : 0.f;
        int4 i4;
        i4.x = y0c * WD + x0c;
        i4.y = y0c * WD + x1c;
        i4.z = y1c * WD + x0c;
        i4.w = y1c * WD + x1c;
        p_w4[t] = w4;
        p_idx4[t] = i4;
    }
    __syncthreads();

    const float* xn = x + (size_t)n * CIN * HW;
    for (int e = t; e < CK * TPF; e += 256) {
        int row = e >> 4, p = e & 15;
        int cc = row / 9, k = row - cc * 9;
        int task = (k << 4) | p;
        float4 w4 = p_w4[task];
        int4  i4 = p_idx4[task];
        const float* xc = xn + (size_t)cc * HW;
        val_f[e] = w4.x * xc[i4.x] + w4.y * xc[i4.y]
                 + w4.z * xc[i4.z] + w4.w * xc[i4.w];
    }
    __syncthreads();

    int o = t & 63, q = t >> 6;
    float4 acc = {0.f, 0.f, 0.f, 0.f};
    const float4* v4 = (const float4*)val_f;
    const float* wp = wt + o;
    #pragma unroll 4
    for (int r = 0; r < CK; r++) {
        float w = wp[r * COUT];
        float4 vv = v4[r * 4 + q];
        acc.x += w * vv.x; acc.y += w * vv.y;
        acc.z += w * vv.z; acc.w += w * vv.w;
    }
    float b = bias[o];
    acc.x += b; acc.y += b; acc.z += b; acc.w += b;
    __syncthreads();
    float4* o4 = (float4*)val_f;
    o4[o * 4 + q] = acc;
    __syncthreads();
    size_t obase = ((size_t)n * COUT) * HW + (size_t)ho * WD + wo0;
    #pragma unroll
    for (int i = 0; i < 4; i++) {
        int l = t + 256 * i;
        int oo = l >> 4, p = l & 15;
        out[obase + (size_t)oo * HW + p] = val_f[l];
    }
}

extern "C" void kernel_launch(void* const* d_in, const int* in_sizes, int n_in,
                              void* d_out, int out_size, void* d_ws, size_t ws_size,
                              hipStream_t stream) {
    const float* x      = (const float*)d_in[0];
    const float* w_off  = (const float*)d_in[1];
    const float* b_off  = (const float*)d_in[2];
    const float* w_mask = (const float*)d_in[3];
    const float* b_mask = (const float*)d_in[4];
    const float* weight = (const float*)d_in[5];
    const float* bias   = (const float*)d_in[6];
    float* out = (float*)d_out;

    // ws layout (shorts): waM_hi | waO_hi | xp
    short* base = (short*)d_ws;
    short* waM_hi = base;
    short* waO_hi = waM_hi + WAM;
    unsigned short* xp = (unsigned short*)(waO_hi + WAO);
    size_t need = ((size_t)WAM + WAO + XTP) * sizeof(short);

    if (ws_size >= need) {
        pre_kernel<<<PRE_T + PRE_H + PRE_P, 256, 0, stream>>>(
            x, weight, w_off, w_mask, xp, waM_hi, waO_hi);
        fused_kernel<<<dim3(WD / TP, HD, NB), 256, 0, stream>>>(
            xp, waM_hi, waO_hi, b_off, b_mask, bias, out);
    } else {
        float* offy = (float*)d_ws;
        float* offx = offy + OFFSZ;
        float* wt   = offx + OFFSZ;
        transpose_w_kernel<<<144, 256, 0, stream>>>(weight, wt);
        offmask_kernel<<<256, 256, 0, stream>>>(x, w_off, b_off, w_mask, b_mask, offy, offx);
        deform_kernel<<<dim3(WD / TPF, HD, NB), 256, 0, stream>>>(x, offy, offx, wt, bias, out);
    }
}

// Round 10
// 108.992 us; speedup vs baseline: 1.7564x; 1.0854x over previous
//
#include <hip/hip_runtime.h>
#include <math.h>

#define HD 128
#define WD 128
#define WP 130              // padded width/height (1-halo)
#define CIN 64
#define COUT 64
#define NB 4
#define K2 9
#define HW (HD*WD)          // 16384
#define CK 576              // CIN*K2, K of both GEMMs (k-major permuted: r' = k*64+c)
#define TP 32               // pixels per block (conv/gather kernels)
#define TPF 16              // pixels per block (fallback kernel)
#define NKK 18              // K-steps of 32

#define WAM   (4 * NKK * 64 * 8)             // 36864 shorts main A-frag buffer (fp16 bits)
#define WAO   (2 * NKK * 64 * 8)             // 18432 shorts offset A-frag buffer (fp16 bits)
#define XTP   ((size_t)NB * WP * WP * CIN)   // 4326400 shorts (padded NHWC fp16 x)
#define OFFSZ ((size_t)NB * K2 * HW)         // 589824 elements per param plane / fallback
#define WTSZ  ((size_t)CK * COUT)            // fallback

// pre_kernel block partition
#define PRE_T 1024                            // transpose blocks
#define PRE_H 65                              // halo-zero blocks
#define PRE_P ((WAM + WAO) / 256)             // 216 prep blocks
#define HALO_PER_N 33024                      // halo shorts per image
#define HALO_W8 16512                         // total 8-short zero units

typedef __attribute__((ext_vector_type(8))) short short8;
typedef __attribute__((ext_vector_type(4))) float f32x4;
typedef _Float16 half8 __attribute__((ext_vector_type(8)));
typedef _Float16 half2v __attribute__((ext_vector_type(2)));

// fp32 -> fp16 bits (scalar, RTN)
__device__ inline short f2h(float v) {
    _Float16 h = (_Float16)v;
    short s; __builtin_memcpy(&s, &h, 2); return s;
}
// pack two fp32 -> dword of two fp16 (v_cvt_pkrtz_f16_f32, 1 instr)
__device__ inline unsigned int pack_f16(float a, float b) {
    auto h = __builtin_amdgcn_cvt_pkrtz(a, b);
    unsigned int u; __builtin_memcpy(&u, &h, 4); return u;
}
// duplicate one fp32 into both halves of a packed fp16 pair
__device__ inline half2v dup_h2(float a) {
    auto h = __builtin_amdgcn_cvt_pkrtz(a, a);
    half2v r; __builtin_memcpy(&r, &h, 4); return r;
}

// ---------------- merged pre-kernel: transpose | halo zero | weight prep (R5-proven) ----------------
__global__ __launch_bounds__(256) void pre_kernel(
    const float* __restrict__ x,
    const float* __restrict__ weight,
    const float* __restrict__ w_off,
    const float* __restrict__ w_mask,
    unsigned short* __restrict__ xp,
    short* __restrict__ mhi, short* __restrict__ ohi)
{
    __shared__ float tile[64][66];   // [w][c], pad 66
    int bid = blockIdx.x;
    int t = threadIdx.x;

    if (bid < PRE_T) {
        int half = bid & 1;
        int h = (bid >> 1) & 127;
        int n = bid >> 8;
        int w0 = half * 64;
        int g = t >> 6, wl = t & 63;
        const float* xb = x + ((size_t)n * CIN) * HW + h * WD + w0;
        #pragma unroll
        for (int i = 0; i < 16; i++) {
            int cc = i * 4 + g;
            tile[wl][cc] = xb[(size_t)cc * HW + wl];
        }
        __syncthreads();
        size_t rowbase = (((size_t)n * WP + (h + 1)) * WP + (w0 + 1)) * CIN;
        #pragma unroll
        for (int i = 0; i < 8; i++) {
            int u = i * 256 + t;
            int ww = u >> 5;
            int cp = (u & 31) * 2;
            float2 v = *(const float2*)&tile[ww][cp];
            *(unsigned int*)&xp[rowbase + (size_t)ww * CIN + cp] = pack_f16(v.x, v.y);
        }
    } else if (bid < PRE_T + PRE_H) {
        int widx = (bid - PRE_T) * 256 + t;
        if (widx < HALO_W8) {
            int s = widx * 8;
            int n = s / HALO_PER_N;
            int v = s - n * HALO_PER_N;
            size_t nb = (size_t)n * WP * WP * CIN;
            size_t base;
            if (v < 8320) {
                base = nb + v;
            } else if (v < 16640) {
                base = nb + (size_t)129 * WP * CIN + (v - 8320);
            } else if (v < 24832) {
                int v2 = v - 16640; int h = 1 + (v2 >> 6); int c = v2 & 63;
                base = nb + (size_t)h * WP * CIN + c;
            } else {
                int v3 = v - 24832; int h = 1 + (v3 >> 6); int c = v3 & 63;
                base = nb + ((size_t)h * WP + 129) * CIN + c;
            }
            short8 z = {0, 0, 0, 0, 0, 0, 0, 0};
            *(short8*)&xp[base] = z;
        }
    } else {
        int gid = (bid - PRE_T - PRE_H) * 256 + t;
        if (gid < WAM) {
            int idx = gid;
            int jj = idx & 7;
            int lane = (idx >> 3) & 63;
            int kk = (idx >> 9) % NKK;
            int mt = (idx >> 9) / NKK;
            int o = mt * 16 + (lane & 15);
            int rp = kk * 32 + (lane >> 4) * 8 + jj;
            int k = rp >> 6, c = rp & 63;
            mhi[idx] = f2h(weight[((size_t)o * CIN + c) * 9 + k]);
        } else {
            int idx = gid - WAM;
            int jj = idx & 7;
            int lane = (idx >> 3) & 63;
            int kk = (idx >> 9) % NKK;
            int mt = (idx >> 9) / NKK;
            int j = mt * 16 + (lane & 15);
            int rp = kk * 32 + (lane >> 4) * 8 + jj;
            int k = rp >> 6, c = rp & 63;
            float w = 0.f;
            if (j < 18)      w = w_off[((size_t)j * CIN + c) * 9 + k];
            else if (j < 27) w = w_mask[((size_t)(j - 18) * CIN + c) * 9 + k];
            ohi[idx] = f2h(w);
        }
    }
}

// ---------------- conv kernel: R5 stages 1+2+3; params -> global planes ----------------
// grid (WD/TP=4, HD, NB), block 256, 4 blocks/CU (40320 B LDS), 2 barriers.
__global__ __launch_bounds__(256, 4) void conv_kernel(
    const unsigned short* __restrict__ xp,
    const short* __restrict__ waO_hi,
    const float* __restrict__ b_off, const float* __restrict__ b_mask,
    float* __restrict__ wyP, float* __restrict__ wxP,
    unsigned int* __restrict__ metaP)
{
    // B operand: 72 chunks x (32 p-slots x 8 jj) fp16, slot = (p + c2) & 31
    __shared__ __align__(16) short val_s[72 * 256];      // 36864 B
    __shared__ __align__(16) float U[27 * 32];           // 3456 B (conv outputs, bias added)

    int t = threadIdx.x;
    int wv = t >> 6;
    int lane = t & 63;
    int wo0 = blockIdx.x * TP;
    int ho  = blockIdx.y;
    int n   = blockIdx.z;
    const unsigned short* xpn = xp + (size_t)n * WP * WP * CIN;
    int p16 = lane & 15, quad = lane >> 4;

    // ---- stage 1: patch -> B-frag layout; 2304 16B copies (9 exact iters) ----
    #pragma unroll
    for (int i = 0; i < 9; i++) {
        int u = t + 256 * i;
        int tap = u >> 8;
        int p = (u >> 3) & 31;
        int g = u & 7;
        int ti = tap / 3, tj = tap - ti * 3;
        const short8 v = *(const short8*)&xpn[((size_t)(ho + ti) * WP + (wo0 + p + tj)) * CIN + g * 8];
        int c2 = tap * 8 + g;
        *(short8*)&val_s[c2 * 256 + ((p + c2) & 31) * 8] = v;
    }
    __syncthreads();

    // ---- stage 2: offset/mask conv GEMM on waves 0-1; single-A, dual-B (p-halves) ----
    if (wv < 2) {
        int jt = wv;
        f32x4 c0a = {0.f, 0.f, 0.f, 0.f};
        f32x4 c1a = {0.f, 0.f, 0.f, 0.f};
        #pragma unroll
        for (int kk = 0; kk < NKK; kk++) {
            int abase = ((jt * NKK + kk) * 64 + lane) * 8;
            half8 ah = *(const half8*)&waO_hi[abase];
            int c2 = kk * 4 + quad;
            half8 b0 = *(const half8*)&val_s[c2 * 256 + ((p16 + c2) & 31) * 8];
            half8 b1 = *(const half8*)&val_s[c2 * 256 + ((16 + p16 + c2) & 31) * 8];
            c0a = __builtin_amdgcn_mfma_f32_16x16x32_f16(ah, b0, c0a, 0, 0, 0);
            c1a = __builtin_amdgcn_mfma_f32_16x16x32_f16(ah, b1, c1a, 0, 0, 0);
        }
        #pragma unroll
        for (int i = 0; i < 4; i++) {
            int j = jt * 16 + quad * 4 + i;
            if (j < 27) {
                float bv = (j < 18) ? b_off[j] : b_mask[j - 18];
                U[j * 32 + p16] = c0a[i] + bv;
                U[j * 32 + 16 + p16] = c1a[i] + bv;
            }
        }
    }
    __syncthreads();

    // ---- stage 3: sigmoid-modulated offsets -> compressed params, straight to global ----
    #pragma unroll
    for (int pass = 0; pass < 2; pass++) {
        int u = t + pass * 256;
        if (u < K2 * TP) {
            int k = u >> 5, p = u & 31;
            float oy_raw = U[(2 * k) * 32 + p];
            float ox_raw = U[(2 * k + 1) * 32 + p];
            float my = 1.f / (1.f + expf(-U[(18 + (2 * k) % 9) * 32 + p]));
            float mx = 1.f / (1.f + expf(-U[(18 + (2 * k + 1) % 9) * 32 + p]));
            float oy = oy_raw * my;
            float ox = ox_raw * mx;
            int ki = k / 3, kj = k - ki * 3;
            int wo = wo0 + p;
            float py = (float)(ho - 1 + ki) + oy;
            float px = (float)(wo - 1 + kj) + ox;
            float y0f = floorf(py), x0f = floorf(px);
            float wy = py - y0f, wx = px - x0f;
            int y0 = (int)y0f, x0 = (int)x0f;
            int y0c = min(max(y0, 0), HD - 1);
            int y1c = min(max(y0 + 1, 0), HD - 1);
            int x0c = min(max(x0, 0), WD - 1);
            int x1c = min(max(x0 + 1, 0), WD - 1);
            bool vy0 = (y0 >= 0) && (y0 < HD);
            bool vy1 = (y0 + 1 >= 0) && (y0 + 1 < HD);
            bool vx0 = (x0 >= 0) && (x0 < WD);
            bool vx1 = (x0 + 1 >= 0) && (x0 + 1 < WD);
            unsigned int meta = (unsigned int)y0c | ((unsigned int)x0c << 7)
                | ((unsigned int)(y1c - y0c) << 14) | ((unsigned int)(x1c - x0c) << 15)
                | ((vy0 && vx0) ? 0x10000u : 0u) | ((vy0 && vx1) ? 0x20000u : 0u)
                | ((vy1 && vx0) ? 0x40000u : 0u) | ((vy1 && vx1) ? 0x80000u : 0u);
            size_t pi = (size_t)(n * K2 + k) * HW + (size_t)ho * WD + wo;
            wyP[pi] = wy;
            wxP[pi] = wx;
            metaP[pi] = meta;
        }
    }
}

// ---------------- gather kernel: params-load + gather + GEMM, ONE barrier (R8-proven) ----------------
// grid (WD/TP=4, HD, NB), block 256, 4 blocks/CU (36864 B LDS).
__global__ __launch_bounds__(256, 4) void gather_kernel(
    const unsigned short* __restrict__ xp,
    const short* __restrict__ waM_hi,
    const float* __restrict__ wyP, const float* __restrict__ wxP,
    const unsigned int* __restrict__ metaP,
    const float* __restrict__ bias,
    float* __restrict__ out)
{
    // B operand: 72 chunks x (32 p-slots x 8 jj) fp16, slot = (p + c2) & 31
    __shared__ __align__(16) short val_s[72 * 256];      // 36864 B

    int t = threadIdx.x;
    int wv = t >> 6;
    int lane = t & 63;
    int wo0 = blockIdx.x * TP;
    int ho  = blockIdx.y;
    int n   = blockIdx.z;
    const unsigned short* xpn = xp + (size_t)n * WP * WP * CIN;
    int p16 = lane & 15, quad = lane >> 4;

    // ---- main-GEMM A prefetch: kk 0..7, independent of the gather ----
    half8 apre[8];
    #pragma unroll
    for (int kk = 0; kk < 8; kk++)
        apre[kk] = *(const half8*)&waM_hi[((wv * NKK + kk) * 64 + lane) * 8];

    // ---- gather: thread owns pixel p = t>>3, group g = t&7; k = iter ----
    {
        int p = t >> 3, g = t & 7, c0 = g * 8;
        size_t pbase = (size_t)(n * K2) * HW + (size_t)ho * WD + wo0 + p;
        #pragma unroll
        for (int i = 0; i < 9; i++) {
            size_t pi = pbase + (size_t)i * HW;
            float wy = wyP[pi];
            float wx = wxP[pi];
            unsigned int m = metaP[pi];
            float wy0 = 1.f - wy, wx0 = 1.f - wx;
            float wA = (m & 0x10000u) ? wy0 * wx0 : 0.f;
            float wB = (m & 0x20000u) ? wy0 * wx  : 0.f;
            float wC = (m & 0x40000u) ? wy  * wx0 : 0.f;
            float wD = (m & 0x80000u) ? wy  * wx  : 0.f;
            half2v wa2 = dup_h2(wA), wb2 = dup_h2(wB), wc2 = dup_h2(wC), wd2 = dup_h2(wD);
            int y0c = (int)(m & 127u);
            int x0c = (int)((m >> 7) & 127u);
            int ry0 = (y0c + 1) * (WP * CIN);
            int ry1 = ry0 + (int)((m >> 14) & 1u) * (WP * CIN);
            int cx0 = (x0c + 1) * CIN + c0;
            int cx1 = (x0c + 1) * CIN + (int)((m >> 15) & 1u) * CIN + c0;
            uint4 qa = *(const uint4*)&xpn[ry0 + cx0];
            uint4 qb = *(const uint4*)&xpn[ry0 + cx1];
            uint4 qc = *(const uint4*)&xpn[ry1 + cx0];
            uint4 qd = *(const uint4*)&xpn[ry1 + cx1];
            unsigned int qa_[4] = {qa.x, qa.y, qa.z, qa.w};
            unsigned int qb_[4] = {qb.x, qb.y, qb.z, qb.w};
            unsigned int qc_[4] = {qc.x, qc.y, qc.z, qc.w};
            unsigned int qd_[4] = {qd.x, qd.y, qd.z, qd.w};
            unsigned int r_[4];
            #pragma unroll
            for (int d = 0; d < 4; d++) {
                half2v ha, hb, hc, hd;
                __builtin_memcpy(&ha, &qa_[d], 4);
                __builtin_memcpy(&hb, &qb_[d], 4);
                __builtin_memcpy(&hc, &qc_[d], 4);
                __builtin_memcpy(&hd, &qd_[d], 4);
                half2v gg = wa2 * ha + wb2 * hb + wc2 * hc + wd2 * hd;   // 4x v_pk_fma_f16
                __builtin_memcpy(&r_[d], &gg, 4);
            }
            uint4 r = {r_[0], r_[1], r_[2], r_[3]};
            int c2 = i * 8 + g;
            *(uint4*)&val_s[c2 * 256 + ((p + c2) & 31) * 8] = r;
        }
    }
    __syncthreads();

    // ---- main GEMM C[64 o][32 p] (fp16 MFMA); kk 0..7 A from prefetch regs ----
    f32x4 a0 = {0.f, 0.f, 0.f, 0.f};
    f32x4 a1 = {0.f, 0.f, 0.f, 0.f};
    #pragma unroll
    for (int kk = 0; kk < NKK; kk++) {
        half8 ah;
        if (kk < 8) ah = apre[kk];
        else        ah = *(const half8*)&waM_hi[((wv * NKK + kk) * 64 + lane) * 8];
        int c2 = kk * 4 + quad;
        half8 b0 = *(const half8*)&val_s[c2 * 256 + ((p16 + c2) & 31) * 8];
        half8 b1 = *(const half8*)&val_s[c2 * 256 + ((16 + p16 + c2) & 31) * 8];
        a0 = __builtin_amdgcn_mfma_f32_16x16x32_f16(ah, b0, a0, 0, 0, 0);
        a1 = __builtin_amdgcn_mfma_f32_16x16x32_f16(ah, b1, a1, 0, 0, 0);
    }

    // ---- epilogue: direct stores ----
    size_t obase = ((size_t)n * COUT) * HW + (size_t)ho * WD + wo0;
    #pragma unroll
    for (int i = 0; i < 4; i++) {
        int o = wv * 16 + quad * 4 + i;
        float bv = bias[o];
        out[obase + (size_t)o * HW + p16] = a0[i] + bv;
        out[obase + (size_t)o * HW + 16 + p16] = a1[i] + bv;
    }
}

// ================= fallback path (R1-proven, fp32 NCHW, TPF=16) =================
__global__ void transpose_w_kernel(const float* __restrict__ w, float* __restrict__ wt) {
    int i = blockIdx.x * 256 + threadIdx.x;
    int o = i / CK;
    int ck = i - o * CK;
    wt[ck * COUT + o] = w[i];
}

__global__ __launch_bounds__(256) void offmask_kernel(
    const float* __restrict__ x,
    const float* __restrict__ w_off, const float* __restrict__ b_off,
    const float* __restrict__ w_mask, const float* __restrict__ b_mask,
    float* __restrict__ offy, float* __restrict__ offx)
{
    __shared__ float ws[CK][27];
    int t = threadIdx.x;
    for (int i = t; i < CK * 27; i += 256) {
        int j = i % 27;
        int citap = i / 27;
        int ci = citap / 9;
        int tap = citap - ci * 9;
        float v;
        if (j < 18) v = w_off[(j * CIN + ci) * 9 + tap];
        else        v = w_mask[((j - 18) * CIN + ci) * 9 + tap];
        ws[citap][j] = v;
    }
    __syncthreads();

    int pix = blockIdx.x * 256 + t;
    int n  = pix >> 14;
    int ho = (pix >> 7) & 127;
    int wo = pix & 127;

    float acc[27];
    #pragma unroll
    for (int j = 0; j < 18; j++) acc[j] = b_off[j];
    #pragma unroll
    for (int j = 0; j < 9; j++)  acc[18 + j] = b_mask[j];

    int offs[9];
    bool oks[9];
    #pragma unroll
    for (int dy = 0; dy < 3; dy++) {
        int y = ho - 1 + dy;
        #pragma unroll
        for (int dx = 0; dx < 3; dx++) {
            int xx = wo - 1 + dx;
            bool ok = (y >= 0) && (y < HD) && (xx >= 0) && (xx < WD);
            oks[dy * 3 + dx] = ok;
            offs[dy * 3 + dx] = (ok ? y : 0) * WD + (ok ? xx : 0);
        }
    }
    const float* xn = x + (size_t)n * CIN * HW;
    for (int ci = 0; ci < CIN; ci++) {
        const float* xc = xn + (size_t)ci * HW;
        float v[9];
        #pragma unroll
        for (int tap = 0; tap < 9; tap++)
            v[tap] = oks[tap] ? xc[offs[tap]] : 0.f;
        #pragma unroll
        for (int tap = 0; tap < 9; tap++) {
            const float* wrow = ws[ci * 9 + tap];
            float vv = v[tap];
            #pragma unroll
            for (int j = 0; j < 27; j++) acc[j] += wrow[j] * vv;
        }
    }
    float m[9];
    #pragma unroll
    for (int j = 0; j < 9; j++) m[j] = 1.f / (1.f + expf(-acc[18 + j]));
    #pragma unroll
    for (int k = 0; k < 9; k++) {
        int cy = 2 * k, cx = 2 * k + 1;
        float my = m[cy < 9 ? cy : cy - 9];
        float mx = m[cx < 9 ? cx : cx - 9];
        size_t o = (((size_t)n * K2 + k) * HD + ho) * WD + wo;
        offy[o] = acc[cy] * my;
        offx[o] = acc[cx] * mx;
    }
}

__global__ __launch_bounds__(256) void deform_kernel(
    const float* __restrict__ x,
    const float* __restrict__ offy, const float* __restrict__ offx,
    const float* __restrict__ wt,
    const float* __restrict__ bias,
    float* __restrict__ out)
{
    __shared__ __align__(16) float val_f[CK * TPF];
    __shared__ float4 p_w4[K2 * TPF];
    __shared__ int4   p_idx4[K2 * TPF];

    int t = threadIdx.x;
    int wo0 = blockIdx.x * TPF;
    int ho  = blockIdx.y;
    int n   = blockIdx.z;

    if (t < K2 * TPF) {
        int k = t >> 4, p = t & 15;
        int wo = wo0 + p;
        size_t oi = (((size_t)n * K2 + k) * HD + ho) * WD + wo;
        float oy = offy[oi], ox = offx[oi];
        int ki = k / 3, kj = k - ki * 3;
        float py = (float)(ho - 1 + ki) + oy;
        float px = (float)(wo - 1 + kj) + ox;
        float y0f = floorf(py), x0f = floorf(px);
        float wy = py - y0f, wx = px - x0f;
        int y0 = (int)y0f, x0 = (int)x0f;
        float wy0 = 1.f - wy, wx0 = 1.f - wx;
        int y0c = min(max(y0, 0), HD - 1);
        int y1c = min(max(y0 + 1, 0), HD - 1);
        int x0c = min(max(x0, 0), WD - 1);
        int x1c = min(max(x0 + 1, 0), WD - 1);
        bool vy0 = (y0 >= 0) && (y0 < HD);
        bool vy1 = (y0 + 1 >= 0) && (y0 + 1 < HD);
        bool vx0 = (x0 >= 0) && (x0 < WD);
        bool vx1 = (x0 + 1 >= 0) && (x0 + 1 < WD);
        float4 w4;
        w4.x = (vy0 && vx0) ? wy0 * wx0 : 0.f;
        w4.y = (vy0 && vx1) ? wy0 * wx  : 0.f;
        w4.z = (vy1 && vx0) ? wy  * wx0 : 0.f;
        w4.w = (vy1 && vx1) ? wy  * wx  : 0.f;
        int4 i4;
        i4.x = y0c * WD + x0c;
        i4.y = y0c * WD + x1c;
        i4.z = y1c * WD + x0c;
        i4.w = y1c * WD + x1c;
        p_w4[t] = w4;
        p_idx4[t] = i4;
    }
    __syncthreads();

    const float* xn = x + (size_t)n * CIN * HW;
    for (int e = t; e < CK * TPF; e += 256) {
        int row = e >> 4, p = e & 15;
        int cc = row / 9, k = row - cc * 9;
        int task = (k << 4) | p;
        float4 w4 = p_w4[task];
        int4  i4 = p_idx4[task];
        const float* xc = xn + (size_t)cc * HW;
        val_f[e] = w4.x * xc[i4.x] + w4.y * xc[i4.y]
                 + w4.z * xc[i4.z] + w4.w * xc[i4.w];
    }
    __syncthreads();

    int o = t & 63, q = t >> 6;
    float4 acc = {0.f, 0.f, 0.f, 0.f};
    const float4* v4 = (const float4*)val_f;
    const float* wp = wt + o;
    #pragma unroll 4
    for (int r = 0; r < CK; r++) {
        float w = wp[r * COUT];
        float4 vv = v4[r * 4 + q];
        acc.x += w * vv.x; acc.y += w * vv.y;
        acc.z += w * vv.z; acc.w += w * vv.w;
    }
    float b = bias[o];
    acc.x += b; acc.y += b; acc.z += b; acc.w += b;
    __syncthreads();
    float4* o4 = (float4*)val_f;
    o4[o * 4 + q] = acc;
    __syncthreads();
    size_t obase = ((size_t)n * COUT) * HW + (size_t)ho * WD + wo0;
    #pragma unroll
    for (int i = 0; i < 4; i++) {
        int l = t + 256 * i;
        int oo = l >> 4, p = l & 15;
        out[obase + (size_t)oo * HW + p] = val_f[l];
    }
}

extern "C" void kernel_launch(void* const* d_in, const int* in_sizes, int n_in,
                              void* d_out, int out_size, void* d_ws, size_t ws_size,
                              hipStream_t stream) {
    const float* x      = (const float*)d_in[0];
    const float* w_off  = (const float*)d_in[1];
    const float* b_off  = (const float*)d_in[2];
    const float* w_mask = (const float*)d_in[3];
    const float* b_mask = (const float*)d_in[4];
    const float* weight = (const float*)d_in[5];
    const float* bias   = (const float*)d_in[6];
    float* out = (float*)d_out;

    // ws layout: waM | waO (shorts) | xp (ushorts) | wyP | wxP (f32) | metaP (u32)
    short* waM_hi = (short*)d_ws;
    short* waO_hi = waM_hi + WAM;
    unsigned short* xp = (unsigned short*)(waO_hi + WAO);
    float* wyP = (float*)(xp + XTP);
    float* wxP = wyP + OFFSZ;
    unsigned int* metaP = (unsigned int*)(wxP + OFFSZ);
    size_t need = ((size_t)WAM + WAO + XTP) * 2 + (size_t)OFFSZ * 12;

    if (ws_size >= need) {
        pre_kernel<<<PRE_T + PRE_H + PRE_P, 256, 0, stream>>>(
            x, weight, w_off, w_mask, xp, waM_hi, waO_hi);
        conv_kernel<<<dim3(WD / TP, HD, NB), 256, 0, stream>>>(
            xp, waO_hi, b_off, b_mask, wyP, wxP, metaP);
        gather_kernel<<<dim3(WD / TP, HD, NB), 256, 0, stream>>>(
            xp, waM_hi, wyP, wxP, metaP, bias, out);
    } else {
        float* offy = (float*)d_ws;
        float* offx = offy + OFFSZ;
        float* wt   = offx + OFFSZ;
        transpose_w_kernel<<<144, 256, 0, stream>>>(weight, wt);
        offmask_kernel<<<256, 256, 0, stream>>>(x, w_off, b_off, w_mask, b_mask, offy, offx);
        deform_kernel<<<dim3(WD / TPF, HD, NB), 256, 0, stream>>>(x, offy, offx, wt, bias, out);
    }
}